// Round 6
// baseline (11652.305 us; speedup 1.0000x reference)
//
#include <hip/hip_runtime.h>
#include <hip/hip_bf16.h>
#include <math.h>

#define BB 512
#define HH 512
#define TT 1024

typedef __bf16 bf16;
typedef __bf16 bf16x8 __attribute__((ext_vector_type(8)));
typedef float f32x4 __attribute__((ext_vector_type(4)));
typedef unsigned long long ull;
typedef ull ull2 __attribute__((ext_vector_type(2)));

#define SENT 0x7FC07FC07FC07FC0ULL   // 4x bf16 NaN — h = so*tanh(c) is never NaN

// ---------------- ws layout (bytes) ----------------
// WcT : [2048][512] bf16 @ 0      (2 MB)  folded: Whh + Wfc ⊗ Wih
// biasC: [2048] f32      @ 2 MB   (8 KB)
// HL  : 3 x [512][512] bf16 local-copy rotating buffers  (1.5 MB)
// HM  : 3 x [512][512] bf16 MALL-copy rotating buffers   (1.5 MB)
#define WT_OFF 0
#define BC_OFF (2*1024*1024)
#define HL_OFF (BC_OFF + 8192)
#define HM_OFF (HL_OFF + 3*512*1024)

__global__ void prep_weights(const float* __restrict__ Whh, const float* __restrict__ Wih,
                             const float* __restrict__ bih, const float* __restrict__ bhh,
                             const float* __restrict__ Wfc, const float* __restrict__ bfc,
                             bf16* __restrict__ WcT, float* __restrict__ biasC) {
    int col = blockIdx.x;                 // 0..2047
    float wih = Wih[col];
    for (int k = threadIdx.x; k < HH; k += blockDim.x)
        WcT[col * HH + k] = (bf16)(Whh[col * HH + k] + Wfc[k] * wih);
    if (threadIdx.x == 0) biasC[col] = bih[col] + bhh[col] + bfc[0] * wih;
}

__global__ void prep_state(const float* __restrict__ h,
                           bf16* __restrict__ l0, bf16* __restrict__ m0,
                           unsigned short* __restrict__ l1, unsigned short* __restrict__ l2,
                           unsigned short* __restrict__ m1, unsigned short* __restrict__ m2) {
    int i = blockIdx.x * blockDim.x + threadIdx.x;
    if (i < BB * HH) {
        bf16 v = (bf16)h[i];
        l0[i] = v;  m0[i] = v;
        l1[i] = 0x7FC0; l2[i] = 0x7FC0;
        m1[i] = 0x7FC0; m2[i] = 0x7FC0;
    }
}

__device__ __forceinline__ float tanh_fast(float x) {
    float ax = fabsf(x);
    float e = __expf(-2.f * ax);
    float r = (1.f - e) / (1.f + e);
    return copysignf(r, x);
}
__device__ __forceinline__ float sigmoid_fast(float x) {
    return 1.f / (1.f + __expf(-x));
}
__device__ __forceinline__ bool has_sent(ull v) {
    ull y = v ^ SENT;
    return ((y - 0x0001000100010001ULL) & ~y & 0x8000800080008000ULL) != 0ULL;
}
__device__ __forceinline__ bool has_sent2(ull2 v) {
    return has_sent(v.x) | has_sent(v.y);
}

// Persistent LSTM. Exchange = dual-copy: local copy via sc0-only (stays in the
// XCD's L2 — producers/consumers of a bt-group are co-XCD under round-robin
// dispatch, pinned to 1 wg/CU by 60KB dynamic LDS), plus a MALL copy via
// sc0 sc1 (correct fallback for ANY placement). NaN-sentinel dataflow, 3
// rotating buffers, clear-behind; no flags, no RMW, no cache-maintenance ops.
__global__ __launch_bounds__(256, 1) void lstm_persist(
    const bf16* __restrict__ WcT,     // [2048][512] bf16 (folded)
    const float* __restrict__ biasC,  // [2048]
    const float* __restrict__ Wih,    // [2048]
    const float* __restrict__ Wfc,    // [512]
    const float* __restrict__ bfc,    // [1]
    const float* __restrict__ c0,     // [512*512] f32
    char* __restrict__ hl,            // 3 x 512KB local copies
    char* __restrict__ hm,            // 3 x 512KB MALL copies
    float* __restrict__ out)          // [512][1024]
{
    extern __shared__ char dynpad[];               // 60KB occupancy pad (unused)
    __shared__ __align__(16) bf16 Alds[32 * 512];  // XOR-swizzled h tile (32 KB)
    __shared__ float xls[32];                      // step-0 correction per row
    __shared__ float WfcLDS[512];
    __shared__ bf16 hrep[32][40];                  // h repack for coalesced stores

    const int tid  = threadIdx.x;
    const int wave = tid >> 6;
    const int lane = tid & 63;
    const int l15  = lane & 15;
    const int hi   = lane >> 4;
    // XCD swizzle: bt-group (16 wgs, fixed bt) = fixed blockIdx&7 => same XCD
    // under round-robin dispatch. Perf-only; MALL copy covers any placement.
    const int xcd = blockIdx.x & 7;
    const int ii  = blockIdx.x >> 3;
    const int bt  = xcd * 2 + (ii & 1);       // 0..15
    const int hs  = ii >> 1;                  // 0..15

    WfcLDS[tid] = Wfc[tid];
    WfcLDS[tid + 256] = Wfc[tid + 256];

    // ---- preload folded weights into registers ----
    bf16x8 breg[2][16];
    float biasr[2], wihr[2];
    #pragma unroll
    for (int nt = 0; nt < 2; ++nt) {
        int gcol = (nt * 2 + (l15 >> 3)) * HH + hs * 32 + wave * 8 + (l15 & 7);
        const bf16* wp = WcT + (size_t)gcol * HH + hi * 8;
        #pragma unroll
        for (int kk = 0; kk < 16; ++kk)
            breg[nt][kk] = *(const bf16x8*)(wp + kk * 32);
        biasr[nt] = biasC[gcol];
        wihr[nt]  = Wih[gcol];
    }
    const bool lo = (l15 < 8);
    float p0 = __shfl_xor(biasr[0], 8), p1 = __shfl_xor(biasr[1], 8);
    const float bI = lo ? biasr[0] : p0, bF = lo ? p0 : biasr[0];
    const float bG = lo ? biasr[1] : p1, bO = lo ? p1 : biasr[1];
    p0 = __shfl_xor(wihr[0], 8); p1 = __shfl_xor(wihr[1], 8);
    const float wI = lo ? wihr[0] : p0, wF = lo ? p0 : wihr[0];
    const float wG = lo ? wihr[1] : p1, wO = lo ? p1 : wihr[1];

    const int mymt = lo ? 0 : 1;
    const int jcol = wave * 8 + (l15 & 7);    // col within slice (0..31)
    const int jloc = hs * 32 + jcol;
    float creg[4];
    #pragma unroll
    for (int r = 0; r < 4; ++r) {
        int brow = bt * 32 + mymt * 16 + hi * 4 + r;
        creg[r] = c0[(size_t)brow * HH + jloc];
    }
    const float bfcv = bfc[0];

    const int swz = l15 & 7;
    const int row = tid >> 3;                 // staging row 0..31
    const int seg = tid & 7;
    const int r7  = row & 7;

    // per-thread byte addresses:
    //  read base  rd(X) = X + (bt*32+row)*1024 + seg*128   (8 granules x 16B)
    //  write addr wr(X) = rd(X) + hs*64 - seg*120          (own 8B granule-half)
    const size_t rdoff  = ((size_t)(bt * 32 + row)) * 1024 + (size_t)seg * 128;
    const int    wdelta = hs * 64 - seg * 120;
    char* rlA = hl + rdoff;                 char* rmA = hm + rdoff;
    char* rlB = hl + 512 * 1024 + rdoff;    char* rmB = hm + 512 * 1024 + rdoff;
    char* rlC = hl + 1024 * 1024 + rdoff;   char* rmC = hm + 1024 * 1024 + rdoff;

    __syncthreads();   // WfcLDS ready

    for (int s = 0; s <= TT; ++s) {
        if (s == TT && hs != 0) break;      // only hs==0 needs the final tile

        // 1. stage A_s tile: poll local-L2 copy (sc0); after 8 spins also
        //    poll the MALL copy (sc0 sc1); accept whichever is non-sentinel.
        {
            unsigned am = 0;
            int spins = 0;
            while (am != 0xFFu) {
                ull2 q0, q1, q2, q3, q4, q5, q6, q7;
                asm volatile(
                    "global_load_dwordx4 %0, %8, off sc0\n\t"
                    "global_load_dwordx4 %1, %8, off offset:16 sc0\n\t"
                    "global_load_dwordx4 %2, %8, off offset:32 sc0\n\t"
                    "global_load_dwordx4 %3, %8, off offset:48 sc0\n\t"
                    "global_load_dwordx4 %4, %8, off offset:64 sc0\n\t"
                    "global_load_dwordx4 %5, %8, off offset:80 sc0\n\t"
                    "global_load_dwordx4 %6, %8, off offset:96 sc0\n\t"
                    "global_load_dwordx4 %7, %8, off offset:112 sc0\n\t"
                    "s_waitcnt vmcnt(0)"
                    : "=&v"(q0), "=&v"(q1), "=&v"(q2), "=&v"(q3),
                      "=&v"(q4), "=&v"(q5), "=&v"(q6), "=&v"(q7)
                    : "v"(rlA) : "memory");
#define ACCEPT(u, qq)                                                         \
                if (!(am & (1u << u)) && !has_sent2(qq)) {                    \
                    int c_ = seg * 8 + u;                                     \
                    *(ull2*)(Alds + row * 512 + ((c_ ^ r7) << 3)) = qq;       \
                    am |= 1u << u;                                            \
                }
                ACCEPT(0, q0) ACCEPT(1, q1) ACCEPT(2, q2) ACCEPT(3, q3)
                ACCEPT(4, q4) ACCEPT(5, q5) ACCEPT(6, q6) ACCEPT(7, q7)

                if (am != 0xFFu && spins >= 8) {
                    ull2 m0, m1, m2, m3, m4, m5, m6, m7;
                    asm volatile(
                        "global_load_dwordx4 %0, %8, off sc0 sc1\n\t"
                        "global_load_dwordx4 %1, %8, off offset:16 sc0 sc1\n\t"
                        "global_load_dwordx4 %2, %8, off offset:32 sc0 sc1\n\t"
                        "global_load_dwordx4 %3, %8, off offset:48 sc0 sc1\n\t"
                        "global_load_dwordx4 %4, %8, off offset:64 sc0 sc1\n\t"
                        "global_load_dwordx4 %5, %8, off offset:80 sc0 sc1\n\t"
                        "global_load_dwordx4 %6, %8, off offset:96 sc0 sc1\n\t"
                        "global_load_dwordx4 %7, %8, off offset:112 sc0 sc1\n\t"
                        "s_waitcnt vmcnt(0)"
                        : "=&v"(m0), "=&v"(m1), "=&v"(m2), "=&v"(m3),
                          "=&v"(m4), "=&v"(m5), "=&v"(m6), "=&v"(m7)
                        : "v"(rmA) : "memory");
                    ACCEPT(0, m0) ACCEPT(1, m1) ACCEPT(2, m2) ACCEPT(3, m3)
                    ACCEPT(4, m4) ACCEPT(5, m5) ACCEPT(6, m6) ACCEPT(7, m7)
                }
#undef ACCEPT
                if (am != 0xFFu) { ++spins; __builtin_amdgcn_s_sleep(1); }
            }
        }
        __syncthreads();   // full A_s staged => whole group finished iter s-1

        // 2. clear-behind: sentinel my granule in buf[(s+2)%3], both copies
        {
            ull sv = SENT;
            asm volatile(
                "global_store_dwordx2 %0, %2, off sc0\n\t"
                "global_store_dwordx2 %1, %2, off sc0 sc1"
                :: "v"(rlC + wdelta), "v"(rmC + wdelta), "v"(sv) : "memory");
        }

        // 3. FC: step-0 correction (all wgs) and/or y-output (hs==0)
        if (s == 0 || hs == 0) {
            float xacc = 0.f;
            const bf16* arow = Alds + row * 512;
            #pragma unroll
            for (int u = 0; u < 8; ++u) {
                int cc = seg * 8 + u;
                bf16x8 v = *(const bf16x8*)(arow + ((cc ^ r7) << 3));
                const float* wv = WfcLDS + cc * 8;
                #pragma unroll
                for (int e = 0; e < 8; ++e) xacc += (float)v[e] * wv[e];
            }
            xacc += __shfl_xor(xacc, 1);
            xacc += __shfl_xor(xacc, 2);
            xacc += __shfl_xor(xacc, 4);
            xacc += bfcv;
            if (seg == 0) {
                xls[row] = xacc;
                if (hs == 0 && s > 0)
                    out[((size_t)(bt * 32 + row)) * TT + (s - 1)] = xacc;
            }
        }

        if (s == TT) break;                 // epilogue done (y[TT-1] emitted)

        // 4. MFMA: [32,512] @ [512, 32 B-rows]; A from swizzled LDS, B from regs
        f32x4 acc[2][2];
        #pragma unroll
        for (int i = 0; i < 2; ++i)
            #pragma unroll
            for (int j = 0; j < 2; ++j) acc[i][j] = (f32x4)0.f;

        #pragma unroll
        for (int kk = 0; kk < 16; ++kk) {
            int ch = ((hi + 4 * kk) ^ swz) << 3;
            bf16x8 a0 = *(const bf16x8*)(Alds + l15 * 512 + ch);
            bf16x8 a1 = *(const bf16x8*)(Alds + (l15 + 16) * 512 + ch);
            acc[0][0] = __builtin_amdgcn_mfma_f32_16x16x32_bf16(a0, breg[0][kk], acc[0][0], 0, 0, 0);
            acc[0][1] = __builtin_amdgcn_mfma_f32_16x16x32_bf16(a0, breg[1][kk], acc[0][1], 0, 0, 0);
            acc[1][0] = __builtin_amdgcn_mfma_f32_16x16x32_bf16(a1, breg[0][kk], acc[1][0], 0, 0, 0);
            acc[1][1] = __builtin_amdgcn_mfma_f32_16x16x32_bf16(a1, breg[1][kk], acc[1][1], 0, 0, 0);
        }

        if (s == 0) __syncthreads();   // xls visible for the correction

        // 5. pointwise cell update (folded weights include x-feedback;
        //    s==0 subtracts the x0c*Wih correction since x_0 = 0)
        #pragma unroll
        for (int r = 0; r < 4; ++r) {
            float send0 = lo ? acc[1][0][r] : acc[0][0][r];
            float send1 = lo ? acc[1][1][r] : acc[0][1][r];
            float recv0 = __shfl_xor(send0, 8);
            float recv1 = __shfl_xor(send1, 8);
            float own0  = lo ? acc[0][0][r] : acc[1][0][r];
            float own1  = lo ? acc[0][1][r] : acc[1][1][r];
            int  lrow = mymt * 16 + hi * 4 + r;
            float xc = (s == 0) ? xls[lrow] : 0.f;
            float xi = (lo ? own0 : recv0) + bI - xc * wI;
            float xf = (lo ? recv0 : own0) + bF - xc * wF;
            float xg = (lo ? own1 : recv1) + bG - xc * wG;
            float xo = (lo ? recv1 : own1) + bO - xc * wO;
            float si = sigmoid_fast(xi), sf = sigmoid_fast(xf), so = sigmoid_fast(xo);
            float tg = tanh_fast(xg);
            float cn = sf * creg[r] + si * tg;
            creg[r] = cn;
            hrep[lrow][jcol] = (bf16)(so * tanh_fast(cn));
        }
        __syncthreads();   // hrep complete; Alds reads finished

        // 6. store A_{s+1} granule, both copies. vmcnt(0) first: my sentinel
        //    clear of this same granule (iter s-1) is drained before the data
        //    store issues (same thread, same address => ordered).
        {
            ull val = *(const ull*)&hrep[row][seg * 4];
            asm volatile(
                "s_waitcnt vmcnt(0)\n\t"
                "global_store_dwordx2 %0, %2, off sc0\n\t"
                "global_store_dwordx2 %1, %2, off sc0 sc1"
                :: "v"(rlB + wdelta), "v"(rmB + wdelta), "v"(val) : "memory");
        }

        // rotate buffers: (A,B,C) <- (B,C,A), both copies
        char* t;
        t = rlA; rlA = rlB; rlB = rlC; rlC = t;
        t = rmA; rmA = rmB; rmB = rmC; rmC = t;
    }
}

extern "C" void kernel_launch(void* const* d_in, const int* in_sizes, int n_in,
                              void* d_out, int out_size, void* d_ws, size_t ws_size,
                              hipStream_t stream) {
    const float* h   = (const float*)d_in[0];
    const float* c   = (const float*)d_in[1];
    const float* Wih = (const float*)d_in[2];
    const float* Whh = (const float*)d_in[3];
    const float* bih = (const float*)d_in[4];
    const float* bhh = (const float*)d_in[5];
    const float* Wfc = (const float*)d_in[6];
    const float* bfc = (const float*)d_in[7];
    float* out = (float*)d_out;

    char* ws = (char*)d_ws;
    bf16*  WcT   = (bf16*)(ws + WT_OFF);
    float* biasC = (float*)(ws + BC_OFF);
    char*  hl    = ws + HL_OFF;
    char*  hm    = ws + HM_OFF;

    prep_weights<<<2048, 256, 0, stream>>>(Whh, Wih, bih, bhh, Wfc, bfc, WcT, biasC);
    prep_state<<<1024, 256, 0, stream>>>(h,
        (bf16*)hl, (bf16*)hm,
        (unsigned short*)(hl + 512 * 1024), (unsigned short*)(hl + 1024 * 1024),
        (unsigned short*)(hm + 512 * 1024), (unsigned short*)(hm + 1024 * 1024));
    lstm_persist<<<256, 256, 61440, stream>>>(WcT, biasC, Wih, Wfc, bfc, c,
                                              hl, hm, out);
}

// Round 9
// 5209.594 us; speedup vs baseline: 2.2367x; 2.2367x over previous
//
#include <hip/hip_runtime.h>
#include <hip/hip_bf16.h>
#include <math.h>

#define BB 512
#define HH 512
#define TT 1024

typedef __bf16 bf16;
typedef __bf16 bf16x8 __attribute__((ext_vector_type(8)));
typedef float f32x4 __attribute__((ext_vector_type(4)));
typedef unsigned long long ull;
typedef ull ull2 __attribute__((ext_vector_type(2)));

#define SENT 0x7FC07FC07FC07FC0ULL   // 4x bf16 NaN — h = so*tanh(c) is never NaN

// ---------------- ws layout (bytes) ----------------
// WcT : [2048][512] bf16 @ 0      (2 MB)  folded: Whh + Wfc ⊗ Wih
// biasC: [2048] f32      @ 2 MB   (8 KB)
// hb0/1/2: [512][512] bf16 rotating h buffers (3 x 512 KB)
#define WT_OFF 0
#define BC_OFF (2*1024*1024)
#define H0_OFF (BC_OFF + 8192)
#define H1_OFF (H0_OFF + 512*1024)
#define H2_OFF (H1_OFF + 512*1024)

__global__ void prep_weights(const float* __restrict__ Whh, const float* __restrict__ Wih,
                             const float* __restrict__ bih, const float* __restrict__ bhh,
                             const float* __restrict__ Wfc, const float* __restrict__ bfc,
                             bf16* __restrict__ WcT, float* __restrict__ biasC) {
    int col = blockIdx.x;                 // 0..2047
    float wih = Wih[col];
    for (int k = threadIdx.x; k < HH; k += blockDim.x)
        WcT[col * HH + k] = (bf16)(Whh[col * HH + k] + Wfc[k] * wih);
    if (threadIdx.x == 0) biasC[col] = bih[col] + bhh[col] + bfc[0] * wih;
}

__global__ void prep_state(const float* __restrict__ h, bf16* __restrict__ h0buf,
                           unsigned short* __restrict__ h1buf,
                           unsigned short* __restrict__ h2buf) {
    int i = blockIdx.x * blockDim.x + threadIdx.x;
    if (i < BB * HH) {
        h0buf[i] = (bf16)h[i];
        h1buf[i] = 0x7FC0;    // sentinel
        h2buf[i] = 0x7FC0;
    }
}

__device__ __forceinline__ float tanh_fast(float x) {
    float ax = fabsf(x);
    float e = __expf(-2.f * ax);
    float r = (1.f - e) / (1.f + e);
    return copysignf(r, x);
}
__device__ __forceinline__ float sigmoid_fast(float x) {
    return 1.f / (1.f + __expf(-x));
}
__device__ __forceinline__ bool has_sent(ull v) {
    ull y = v ^ SENT;
    return ((y - 0x0001000100010001ULL) & ~y & 0x8000800080008000ULL) != 0ULL;
}
__device__ __forceinline__ bool has_sent2(ull2 v) {
    return has_sent(v.x) | has_sent(v.y);
}

// Persistent LSTM, round-5 protocol (NaN-sentinel, 3 rotating buffers,
// clear-behind, MALL-only exchange via sc0 sc1 — the ONLY validated
// device-visible path) with transaction-coalesced staging: wave w stages rows
// w*8+j via lane-contiguous 16B loads (64 lanes x 16B = 1KB/instr, full 64B
// lines), 4x fewer MALL transactions than the old 128B-stride pattern.
// Retries re-issue only pending rows. No flags, no RMW, no cache maintenance.
__global__ __launch_bounds__(256, 1) void lstm_persist(
    const bf16* __restrict__ WcT,     // [2048][512] bf16 (folded)
    const float* __restrict__ biasC,  // [2048]
    const float* __restrict__ Wih,    // [2048]
    const float* __restrict__ Wfc,    // [512]
    const float* __restrict__ bfc,    // [1]
    const float* __restrict__ c0,     // [512*512] f32
    char* __restrict__ hbase,         // 3 x 512KB rotating buffers
    float* __restrict__ out)          // [512][1024]
{
    __shared__ __align__(16) bf16 Alds[32 * 512];  // XOR-swizzled h tile (32 KB)
    __shared__ float xls[32];                      // step-0 correction per row
    __shared__ float WfcLDS[512];
    __shared__ bf16 hrep[32][40];                  // h repack for coalesced stores

    const int tid  = threadIdx.x;
    const int wave = tid >> 6;
    const int lane = tid & 63;
    const int l15  = lane & 15;
    const int hi   = lane >> 4;
    // group mapping (XCD swizzle is perf-only; correctness is placement-free)
    const int xcd = blockIdx.x & 7;
    const int ii  = blockIdx.x >> 3;
    const int bt  = xcd * 2 + (ii & 1);       // 0..15
    const int hs  = ii >> 1;                  // 0..15

    WfcLDS[tid] = Wfc[tid];
    WfcLDS[tid + 256] = Wfc[tid + 256];

    // ---- preload folded weights into registers ----
    bf16x8 breg[2][16];
    float biasr[2], wihr[2];
    #pragma unroll
    for (int nt = 0; nt < 2; ++nt) {
        int gcol = (nt * 2 + (l15 >> 3)) * HH + hs * 32 + wave * 8 + (l15 & 7);
        const bf16* wp = WcT + (size_t)gcol * HH + hi * 8;
        #pragma unroll
        for (int kk = 0; kk < 16; ++kk)
            breg[nt][kk] = *(const bf16x8*)(wp + kk * 32);
        biasr[nt] = biasC[gcol];
        wihr[nt]  = Wih[gcol];
    }
    const bool lo = (l15 < 8);
    float p0 = __shfl_xor(biasr[0], 8), p1 = __shfl_xor(biasr[1], 8);
    const float bI = lo ? biasr[0] : p0, bF = lo ? p0 : biasr[0];
    const float bG = lo ? biasr[1] : p1, bO = lo ? p1 : biasr[1];
    p0 = __shfl_xor(wihr[0], 8); p1 = __shfl_xor(wihr[1], 8);
    const float wI = lo ? wihr[0] : p0, wF = lo ? p0 : wihr[0];
    const float wG = lo ? wihr[1] : p1, wO = lo ? p1 : wihr[1];

    const int mymt = lo ? 0 : 1;
    const int jcol = wave * 8 + (l15 & 7);    // col within slice (0..31)
    const int jloc = hs * 32 + jcol;
    float creg[4];
    #pragma unroll
    for (int r = 0; r < 4; ++r) {
        int brow = bt * 32 + mymt * 16 + hi * 4 + r;
        creg[r] = c0[(size_t)brow * HH + jloc];
    }
    const float bfcv = bfc[0];

    const int swz = l15 & 7;
    const int row = tid >> 3;                 // pointwise/store row 0..31
    const int seg = tid & 7;
    const int r7  = row & 7;

    // load base (lane-contiguous): wave w covers rows w*8..w*8+8, lane reads
    // 16B at row*1024 + lane*16; rows j=0..3 via base, j=4..7 via base+4096.
    const size_t grp = ((size_t)(bt * 32 + wave * 8)) * 1024 + (size_t)lane * 16;
    // store addr: 8B at (bt*32+row)*1024 + hs*64 + seg*8
    const size_t sto = ((size_t)(bt * 32 + row)) * 1024 + (size_t)hs * 64 + (size_t)seg * 8;

    char* laA = hbase + grp;                  // buf[s%3]     (read A_s)
    char* laB = hbase + 512 * 1024 + grp;
    char* laC = hbase + 1024 * 1024 + grp;
    char* stA = hbase + sto;
    char* stB = hbase + 512 * 1024 + sto;     // buf[(s+1)%3] (write A_{s+1})
    char* stC = hbase + 1024 * 1024 + sto;    // buf[(s+2)%3] (clear-behind)

    char* aldsW = (char*)Alds + wave * 8 * 1024;   // this wave's 8 LDS rows

    __syncthreads();   // WfcLDS ready

    for (int s = 0; s <= TT; ++s) {
        if (s == TT && hs != 0) break;      // only hs==0 needs the final tile

        // 1. stage A_s tile: per-row lane-contiguous 16B loads (MALL, sc0 sc1),
        //    poll until non-sentinel; re-issue only pending rows.
        {
            char* blo = laA;
            char* bhi = laA + 4096;
            unsigned pend = 0xFFu;
            ull2 q0, q1, q2, q3, q4, q5, q6, q7;
            for (;;) {
                if (pend & 0x01u) asm volatile("global_load_dwordx4 %0, %1, off sc0 sc1"             : "=v"(q0) : "v"(blo) : "memory");
                if (pend & 0x02u) asm volatile("global_load_dwordx4 %0, %1, off offset:1024 sc0 sc1" : "=v"(q1) : "v"(blo) : "memory");
                if (pend & 0x04u) asm volatile("global_load_dwordx4 %0, %1, off offset:2048 sc0 sc1" : "=v"(q2) : "v"(blo) : "memory");
                if (pend & 0x08u) asm volatile("global_load_dwordx4 %0, %1, off offset:3072 sc0 sc1" : "=v"(q3) : "v"(blo) : "memory");
                if (pend & 0x10u) asm volatile("global_load_dwordx4 %0, %1, off sc0 sc1"             : "=v"(q4) : "v"(bhi) : "memory");
                if (pend & 0x20u) asm volatile("global_load_dwordx4 %0, %1, off offset:1024 sc0 sc1" : "=v"(q5) : "v"(bhi) : "memory");
                if (pend & 0x40u) asm volatile("global_load_dwordx4 %0, %1, off offset:2048 sc0 sc1" : "=v"(q6) : "v"(bhi) : "memory");
                if (pend & 0x80u) asm volatile("global_load_dwordx4 %0, %1, off offset:3072 sc0 sc1" : "=v"(q7) : "v"(bhi) : "memory");
                asm volatile("s_waitcnt vmcnt(0)" ::: "memory");
                __builtin_amdgcn_sched_barrier(0);
#define ACCEPT(J, QQ)                                                          \
                if ((pend & (1u << J)) && !has_sent2(QQ)) {                    \
                    *(ull2*)(aldsW + J * 1024 + ((lane ^ J) << 4)) = QQ;       \
                    pend &= ~(1u << J);                                        \
                }
                ACCEPT(0, q0) ACCEPT(1, q1) ACCEPT(2, q2) ACCEPT(3, q3)
                ACCEPT(4, q4) ACCEPT(5, q5) ACCEPT(6, q6) ACCEPT(7, q7)
#undef ACCEPT
                if (pend == 0) break;
                __builtin_amdgcn_s_sleep(1);
            }
        }
        __syncthreads();   // full A_s staged => whole group finished iter s-1

        // 2. clear-behind: sentinel my granule in buf[(s+2)%3]
        {
            ull sv = SENT;
            asm volatile("global_store_dwordx2 %0, %1, off sc0 sc1"
                         :: "v"(stC), "v"(sv) : "memory");
        }

        // 3. FC: step-0 correction (all wgs) and/or y-output (hs==0)
        if (s == 0 || hs == 0) {
            float xacc = 0.f;
            const bf16* arow = Alds + row * 512;
            #pragma unroll
            for (int u = 0; u < 8; ++u) {
                int cc = seg * 8 + u;
                bf16x8 v = *(const bf16x8*)(arow + ((cc ^ r7) << 3));
                const float* wv = WfcLDS + cc * 8;
                #pragma unroll
                for (int e = 0; e < 8; ++e) xacc += (float)v[e] * wv[e];
            }
            xacc += __shfl_xor(xacc, 1);
            xacc += __shfl_xor(xacc, 2);
            xacc += __shfl_xor(xacc, 4);
            xacc += bfcv;
            if (seg == 0) {
                xls[row] = xacc;
                if (hs == 0 && s > 0)
                    out[((size_t)(bt * 32 + row)) * TT + (s - 1)] = xacc;
            }
        }

        if (s == TT) break;                 // epilogue done (y[TT-1] emitted)

        // 4. MFMA: [32,512] @ [512, 32 B-rows]; A from swizzled LDS, B from regs
        f32x4 acc[2][2];
        #pragma unroll
        for (int i = 0; i < 2; ++i)
            #pragma unroll
            for (int j = 0; j < 2; ++j) acc[i][j] = (f32x4)0.f;

        #pragma unroll
        for (int kk = 0; kk < 16; ++kk) {
            int ch = ((hi + 4 * kk) ^ swz) << 3;
            bf16x8 a0 = *(const bf16x8*)(Alds + l15 * 512 + ch);
            bf16x8 a1 = *(const bf16x8*)(Alds + (l15 + 16) * 512 + ch);
            acc[0][0] = __builtin_amdgcn_mfma_f32_16x16x32_bf16(a0, breg[0][kk], acc[0][0], 0, 0, 0);
            acc[0][1] = __builtin_amdgcn_mfma_f32_16x16x32_bf16(a0, breg[1][kk], acc[0][1], 0, 0, 0);
            acc[1][0] = __builtin_amdgcn_mfma_f32_16x16x32_bf16(a1, breg[0][kk], acc[1][0], 0, 0, 0);
            acc[1][1] = __builtin_amdgcn_mfma_f32_16x16x32_bf16(a1, breg[1][kk], acc[1][1], 0, 0, 0);
        }

        if (s == 0) __syncthreads();   // xls visible for the correction

        // 5. pointwise cell update (folded weights include x-feedback;
        //    s==0 subtracts the x0c*Wih correction since x_0 = 0)
        #pragma unroll
        for (int r = 0; r < 4; ++r) {
            float send0 = lo ? acc[1][0][r] : acc[0][0][r];
            float send1 = lo ? acc[1][1][r] : acc[0][1][r];
            float recv0 = __shfl_xor(send0, 8);
            float recv1 = __shfl_xor(send1, 8);
            float own0  = lo ? acc[0][0][r] : acc[1][0][r];
            float own1  = lo ? acc[0][1][r] : acc[1][1][r];
            int  lrow = mymt * 16 + hi * 4 + r;
            float xc = (s == 0) ? xls[lrow] : 0.f;
            float xi = (lo ? own0 : recv0) + bI - xc * wI;
            float xf = (lo ? recv0 : own0) + bF - xc * wF;
            float xg = (lo ? own1 : recv1) + bG - xc * wG;
            float xo = (lo ? recv1 : own1) + bO - xc * wO;
            float si = sigmoid_fast(xi), sf = sigmoid_fast(xf), so = sigmoid_fast(xo);
            float tg = tanh_fast(xg);
            float cn = sf * creg[r] + si * tg;
            creg[r] = cn;
            hrep[lrow][jcol] = (bf16)(so * tanh_fast(cn));
        }
        __syncthreads();   // hrep complete; Alds reads finished

        // 6. store A_{s+1} granule. vmcnt(0) first: my sentinel clear of this
        //    same granule (iter s-1) drained before the data store issues
        //    (same thread, same address => ordered at the MALL).
        {
            ull val = *(const ull*)&hrep[row][seg * 4];
            asm volatile(
                "s_waitcnt vmcnt(0)\n\t"
                "global_store_dwordx2 %0, %1, off sc0 sc1"
                :: "v"(stB), "v"(val) : "memory");
        }

        // rotate buffers: (A,B,C) <- (B,C,A)
        char* t;
        t = laA; laA = laB; laB = laC; laC = t;
        t = stA; stA = stB; stB = stC; stC = t;
    }
}

extern "C" void kernel_launch(void* const* d_in, const int* in_sizes, int n_in,
                              void* d_out, int out_size, void* d_ws, size_t ws_size,
                              hipStream_t stream) {
    const float* h   = (const float*)d_in[0];
    const float* c   = (const float*)d_in[1];
    const float* Wih = (const float*)d_in[2];
    const float* Whh = (const float*)d_in[3];
    const float* bih = (const float*)d_in[4];
    const float* bhh = (const float*)d_in[5];
    const float* Wfc = (const float*)d_in[6];
    const float* bfc = (const float*)d_in[7];
    float* out = (float*)d_out;

    char* ws = (char*)d_ws;
    bf16*  WcT   = (bf16*)(ws + WT_OFF);
    float* biasC = (float*)(ws + BC_OFF);
    char*  hb    = ws + H0_OFF;

    prep_weights<<<2048, 256, 0, stream>>>(Whh, Wih, bih, bhh, Wfc, bfc, WcT, biasC);
    prep_state<<<1024, 256, 0, stream>>>(h, (bf16*)hb,
        (unsigned short*)(hb + 512 * 1024), (unsigned short*)(hb + 1024 * 1024));
    lstm_persist<<<256, 256, 0, stream>>>(WcT, biasC, Wih, Wfc, bfc, c, hb, out);
}